// Round 10
// baseline (1323.621 us; speedup 1.0000x reference)
//
#include <hip/hip_runtime.h>
#include <hip/hip_bf16.h>
#include <math.h>

#define FEAT_IN 500
#define HID 64
#define NPB 128        // nodes per bucket
#define MAXB 1024      // max buckets (supports n <= 131072)

typedef unsigned int uint;
typedef unsigned short ushort;
typedef __attribute__((ext_vector_type(8))) short bf16x8;
typedef __attribute__((ext_vector_type(4))) float f32x4;

__device__ inline ushort f2bf(float f) {
    uint u = __float_as_uint(f);
    uint r = (u + 0x7fff + ((u >> 16) & 1)) >> 16;
    return (ushort)r;
}

// pack two fp32 -> (bf16(a) | bf16(b)<<16), RNE
__device__ inline uint pk2(float a, float b) {
    uint ua = __float_as_uint(a), ub = __float_as_uint(b);
    ua = ua + 0x7fff + ((ua >> 16) & 1);
    ub = ub + 0x7fff + ((ub >> 16) & 1);
    return (ua >> 16) | (ub & 0xffff0000u);
}

__device__ inline void bf8_unpack(const uint4 v, float f[8]) {
    f[0] = __uint_as_float(v.x << 16);
    f[1] = __uint_as_float(v.x & 0xffff0000u);
    f[2] = __uint_as_float(v.y << 16);
    f[3] = __uint_as_float(v.y & 0xffff0000u);
    f[4] = __uint_as_float(v.z << 16);
    f[5] = __uint_as_float(v.z & 0xffff0000u);
    f[6] = __uint_as_float(v.w << 16);
    f[7] = __uint_as_float(v.w & 0xffff0000u);
}

// ---------------- phase A: per-bucket edge counts (LDS-aggregated) ----------------
__global__ __launch_bounds__(256) void bcnt_kernel(const int* __restrict__ col,
                                                   int* __restrict__ bcnt, int E, int nbkt) {
    __shared__ int cnt[MAXB];
    int tid = threadIdx.x;
    for (int j = tid; j < nbkt; j += 256) cnt[j] = 0;
    __syncthreads();
    int stride = gridDim.x * 256;
    for (int e = blockIdx.x * 256 + tid; e < E; e += stride) {
        atomicAdd(&cnt[col[e] >> 7], 1);
    }
    __syncthreads();
    for (int j = tid; j < nbkt; j += 256) {
        int v = cnt[j];
        if (v) atomicAdd(&bcnt[j], v);
    }
}

// ---------------- phase B: scan bucket counts -> boff, bcur; ptr[n]=E ----------------
__global__ void bscan_kernel(const int* __restrict__ bcnt, int* __restrict__ boff,
                             int* __restrict__ bcur, int* __restrict__ ptr,
                             int nbkt, int n, int E) {
    int lane = threadIdx.x;  // 64 threads
    int run = 0;
    for (int base = 0; base < nbkt; base += 64) {
        int i = base + lane;
        int v = (i < nbkt) ? bcnt[i] : 0;
        int sc = v;
#pragma unroll
        for (int d = 1; d < 64; d <<= 1) {
            int t = __shfl_up(sc, d);
            if (lane >= d) sc += t;
        }
        if (i < nbkt) {
            int ex = run + sc - v;
            boff[i] = ex;
            bcur[i] = ex;
        }
        run += __shfl(sc, 63);
    }
    if (lane == 0) {
        boff[nbkt] = E;
        ptr[n] = E;
    }
}

// ---------------- phase C: block-aggregated bucketed scatter ----------------
__global__ __launch_bounds__(1024) void bscat_kernel(const int* __restrict__ row,
                                                     const int* __restrict__ col,
                                                     int* __restrict__ bcur,
                                                     uint* __restrict__ csr_tmp,
                                                     int E, int nbkt) {
    __shared__ int cnt[MAXB];
    __shared__ int pos[MAXB];
    int tid = threadIdx.x;
    int chunk = (E + gridDim.x - 1) / gridDim.x;
    int c0 = blockIdx.x * chunk;
    int c1 = min(E, c0 + chunk);
    for (int j = tid; j < nbkt; j += 1024) cnt[j] = 0;
    __syncthreads();
    for (int e = c0 + tid; e < c1; e += 1024) atomicAdd(&cnt[col[e] >> 7], 1);
    __syncthreads();
    for (int j = tid; j < nbkt; j += 1024) {
        int v = cnt[j];
        pos[j] = v ? atomicAdd(&bcur[j], v) : 0;
    }
    __syncthreads();
    for (int e = c0 + tid; e < c1; e += 1024) {
        int c = col[e];
        int j = c >> 7;
        int r = atomicAdd(&pos[j], 1);
        csr_tmp[r] = ((uint)row[e] << 7) | (uint)(c & (NPB - 1));
    }
}

// ---------------- phase D: per-bucket node sort -> csr_src, ptr, dinv ----------------
__global__ __launch_bounds__(256) void bsort_kernel(const uint* __restrict__ csr_tmp,
                                                    const int* __restrict__ boff,
                                                    int* __restrict__ ptr,
                                                    float* __restrict__ dinv,
                                                    int* __restrict__ csr_src,
                                                    int n) {
    __shared__ int degl[NPB];
    __shared__ int offl[NPB];
    int b = blockIdx.x;
    int tid = threadIdx.x;
    int t0 = boff[b], t1 = boff[b + 1];
    if (tid < NPB) degl[tid] = 0;
    __syncthreads();
    for (int p = t0 + tid; p < t1; p += 256) {
        uint pk = csr_tmp[p];
        atomicAdd(&degl[pk & (NPB - 1)], 1);
    }
    __syncthreads();
    if (tid < 64) {
        int v0 = degl[tid];
        int s0 = v0;
#pragma unroll
        for (int d = 1; d < 64; d <<= 1) {
            int t = __shfl_up(s0, d);
            if (tid >= d) s0 += t;
        }
        int tot0 = __shfl(s0, 63);
        int v1 = degl[64 + tid];
        int s1 = v1;
#pragma unroll
        for (int d = 1; d < 64; d <<= 1) {
            int t = __shfl_up(s1, d);
            if (tid >= d) s1 += t;
        }
        offl[tid] = s0 - v0;
        offl[64 + tid] = tot0 + s1 - v1;
    }
    __syncthreads();
    if (tid < NPB) {
        int node = b * NPB + tid;
        if (node < n) {
            ptr[node] = t0 + offl[tid];
            dinv[node] = rsqrtf((float)(degl[tid] + 1));  // +1 self loop
        }
    }
    __syncthreads();
    for (int p = t0 + tid; p < t1; p += 256) {
        uint pk = csr_tmp[p];
        int l = pk & (NPB - 1);
        int r = t0 + atomicAdd(&offl[l], 1);
        csr_src[r] = (int)(pk >> 7);
    }
}

// -------- swizzle W1 (500x64, pad K->512) and W2 (64x64) into MFMA B-frag order --------
__global__ void swz_kernel(const float* __restrict__ W1, const float* __restrict__ W2,
                           ushort* __restrict__ w1s, ushort* __restrict__ w2s) {
    int idx = blockIdx.x * blockDim.x + threadIdx.x;  // [0, 36864)
    if (idx < 32768) {
        int j = idx & 7;
        int l = (idx >> 3) & 63;
        int t = (idx >> 9) & 3;
        int c = idx >> 11;
        int k = c * 32 + (l >> 4) * 8 + j;
        int nn = t * 16 + (l & 15);
        float v = (k < FEAT_IN) ? W1[(size_t)k * HID + nn] : 0.0f;
        w1s[idx] = f2bf(v);
    } else if (idx < 32768 + 4096) {
        int r = idx - 32768;
        int j = r & 7;
        int l = (r >> 3) & 63;
        int t = (r >> 9) & 3;
        int c = r >> 11;
        int k = c * 32 + (l >> 4) * 8 + j;
        int nn = t * 16 + (l & 15);
        w2s[r] = f2bf(W2[(size_t)k * HID + nn]);
    }
}

// ------------- MFMA MLP, K-split: 2 waves per M-tile (each 8 K-chunks), partials in LDS.
// h=relu(xW1+b1); h2=hW2+b2; A=bf16(dinv*h2) TILE-MAJOR (2 tiles of 32 cols); out=temp[0]*h2
__global__ __launch_bounds__(256) void mlp_kernel(const float* __restrict__ x,
                                                  const ushort* __restrict__ w1s,
                                                  const float* __restrict__ b1,
                                                  const ushort* __restrict__ w2s,
                                                  const float* __restrict__ b2,
                                                  const float* __restrict__ temp,
                                                  const float* __restrict__ dinv,
                                                  ushort* __restrict__ A,
                                                  float* __restrict__ out, int n) {
    __shared__ float pacc[2][2][16][65];   // [tile][khalf][row][col(+pad)]
    __shared__ ushort hls[2][16 * 72];     // bf16 h1 per tile, row stride 72
    const int tid = threadIdx.x;
    const int lane = tid & 63;
    const int wv = tid >> 6;   // 0..3
    const int tl = wv >> 1;    // tile within block
    const int kh = wv & 1;     // K half
    const int g = lane >> 4;
    const int c15 = lane & 15;
    const int nmt = (n + 15) / 16;
    int mt = blockIdx.x * 2 + tl;
    bool mtok = (mt < nmt);
    float t0 = temp[0];
    const size_t half = (size_t)n * 32;    // ushorts per feature-tile of a state

    f32x4 acc[4] = {{0.f, 0.f, 0.f, 0.f}, {0.f, 0.f, 0.f, 0.f},
                    {0.f, 0.f, 0.f, 0.f}, {0.f, 0.f, 0.f, 0.f}};
    int row = mt * 16 + c15;
    bool rok = mtok && (row < n);
    const float* xr = x + (size_t)row * FEAT_IN;

    if (mtok) {
        const int cbeg = kh * 8;
        const int cend = kh ? 15 : 8;  // full chunks; kh=1 tail (c=15) separate
        // pipelined, prefetch distance 2
        float4 L0 = {0.f, 0.f, 0.f, 0.f}, H0 = L0, L1 = L0, H1 = L0;
        if (rok) {
            L0 = *(const float4*)(xr + cbeg * 32 + g * 8);
            H0 = *(const float4*)(xr + cbeg * 32 + g * 8 + 4);
            L1 = *(const float4*)(xr + (cbeg + 1) * 32 + g * 8);
            H1 = *(const float4*)(xr + (cbeg + 1) * 32 + g * 8 + 4);
        }
        for (int c = cbeg; c < cend; c++) {
            float4 Ln = {0.f, 0.f, 0.f, 0.f}, Hn = Ln;
            int cn = c + 2;
            if (rok && cn < cend) {
                Ln = *(const float4*)(xr + cn * 32 + g * 8);
                Hn = *(const float4*)(xr + cn * 32 + g * 8 + 4);
            }
            uint4 au;
            au.x = pk2(L0.x, L0.y);
            au.y = pk2(L0.z, L0.w);
            au.z = pk2(H0.x, H0.y);
            au.w = pk2(H0.z, H0.w);
            bf16x8 a = *(bf16x8*)&au;
            const ushort* wp = w1s + ((size_t)c * 4) * 512 + lane * 8;
#pragma unroll
            for (int t = 0; t < 4; t++) {
                bf16x8 b = *(const bf16x8*)(wp + t * 512);
                acc[t] = __builtin_amdgcn_mfma_f32_16x16x32_bf16(a, b, acc[t], 0, 0, 0);
            }
            L0 = L1; H0 = H1; L1 = Ln; H1 = Hn;
        }
        if (kh) {  // tail chunk c=15 (k = 480..511, valid < 500)
            float v[8];
#pragma unroll
            for (int j = 0; j < 8; j++) {
                int k = 480 + g * 8 + j;
                v[j] = (rok && k < FEAT_IN) ? xr[k] : 0.0f;
            }
            uint4 au;
            au.x = pk2(v[0], v[1]);
            au.y = pk2(v[2], v[3]);
            au.z = pk2(v[4], v[5]);
            au.w = pk2(v[6], v[7]);
            bf16x8 a = *(bf16x8*)&au;
            const ushort* wp = w1s + (size_t)15 * 4 * 512 + lane * 8;
#pragma unroll
            for (int t = 0; t < 4; t++) {
                bf16x8 b = *(const bf16x8*)(wp + t * 512);
                acc[t] = __builtin_amdgcn_mfma_f32_16x16x32_bf16(a, b, acc[t], 0, 0, 0);
            }
        }
        // write partial sums
#pragma unroll
        for (int t = 0; t < 4; t++) {
#pragma unroll
            for (int r = 0; r < 4; r++) {
                pacc[tl][kh][g * 4 + r][t * 16 + c15] = acc[t][r];
            }
        }
    }
    __syncthreads();

    // combine partials -> h1 bf16 (wave (tl,kh) does its tile's col-half)
    if (mtok) {
        int rrow = lane & 15;
        int cg = lane >> 4;
        int colbase = kh * 32 + cg * 8;
#pragma unroll
        for (int cc = 0; cc < 8; cc++) {
            int colc = colbase + cc;
            float h = pacc[tl][0][rrow][colc] + pacc[tl][1][rrow][colc] + b1[colc];
            hls[tl][rrow * 72 + colc] = f2bf(fmaxf(h, 0.0f));
        }
    }
    __syncthreads();
    if (!mtok) return;

    // GEMM2: h1(16x64) @ W2(64x64); wave (tl,kh) computes output cols [kh*32, kh*32+32)
    f32x4 acc2[2] = {{0.f, 0.f, 0.f, 0.f}, {0.f, 0.f, 0.f, 0.f}};
#pragma unroll
    for (int c2 = 0; c2 < 2; c2++) {
        bf16x8 a2 = *(const bf16x8*)(hls[tl] + c15 * 72 + c2 * 32 + g * 8);
#pragma unroll
        for (int tt = 0; tt < 2; tt++) {
            int t = kh * 2 + tt;
            bf16x8 b = *(const bf16x8*)(w2s + ((size_t)(c2 * 4 + t)) * 512 + lane * 8);
            acc2[tt] = __builtin_amdgcn_mfma_f32_16x16x32_bf16(a2, b, acc2[tt], 0, 0, 0);
        }
    }

    // epilogue: A = bf16(dinv*h2) tile-major; out = temp[0]*h2 (flat)
#pragma unroll
    for (int tt = 0; tt < 2; tt++) {
        int t = kh * 2 + tt;   // col block 0..3; tile = t>>1, within-tile col = (t&1)*16+c15
        float b2v = b2[t * 16 + c15];
#pragma unroll
        for (int r = 0; r < 4; r++) {
            int orow = mt * 16 + g * 4 + r;
            if (orow < n) {
                float dres = acc2[tt][r] + b2v;
                A[(size_t)(t >> 1) * half + (size_t)orow * 32 + (t & 1) * 16 + c15] =
                    f2bf(dinv[orow] * dres);
                out[(size_t)orow * HID + t * 16 + c15] = t0 * dres;
            }
        }
    }
}

// ------------- tiled intermediate hop (defer mode): one 64B feature-tile per block ---------
// block b: tile = b&1 (alternates across XCDs -> each XCD serves one 6.4MB tile),
// lane = (slot 0..15, q 0..3). Gather granule = exactly one 64B line per edge.
// T_i = sum_j s[j] + s[i];  s_next[i] = dinv[i]^2 * T_i.  No out access.
__global__ __launch_bounds__(256) void hopt2_kernel(const int* __restrict__ ptr,
                                                    const int* __restrict__ csr_src,
                                                    const float* __restrict__ dinv,
                                                    const ushort* __restrict__ cur,
                                                    ushort* __restrict__ nxt, int n) {
    int b = blockIdx.x;
    int tile = b & 1;
    int grp = b >> 1;
    int wv = threadIdx.x >> 6;
    int lane = threadIdx.x & 63;
    int i = grp * 4 + wv;
    if (i >= n) return;
    const int slot = lane >> 2;   // edge slot 0..15
    const int q = lane & 3;       // 16B piece of the 64B row-tile
    const size_t half_u = (size_t)n * 16;  // uints per tile
    const uint* curt = (const uint*)cur + (size_t)tile * half_u + q * 4;

    int s = ptr[i];
    int e = ptr[i + 1];

    float acc[8] = {0.f, 0.f, 0.f, 0.f, 0.f, 0.f, 0.f, 0.f};
    float accB[8] = {0.f, 0.f, 0.f, 0.f, 0.f, 0.f, 0.f, 0.f};

    int rounds = (e - s + 31) >> 5;   // 32 edges per round (2 batches of 16)
    int p = s + slot;
    int j0 = csr_src[(p      < e) ? p      : 0];
    int j1 = csr_src[(p + 16 < e) ? p + 16 : 0];

    for (int r = 0; r < rounds; r++) {
        int pn = p + 32;
        int k0 = csr_src[(pn      < e) ? pn      : 0];
        int k1 = csr_src[(pn + 16 < e) ? pn + 16 : 0];
        uint4 v0 = *(const uint4*)(curt + (size_t)j0 * 16);
        uint4 v1 = *(const uint4*)(curt + (size_t)j1 * 16);
        float w0 = (p      < e) ? 1.0f : 0.0f;
        float w1 = (p + 16 < e) ? 1.0f : 0.0f;
        float f[8];
        bf8_unpack(v0, f);
#pragma unroll
        for (int t = 0; t < 8; t++) acc[t] += w0 * f[t];
        bf8_unpack(v1, f);
#pragma unroll
        for (int t = 0; t < 8; t++) accB[t] += w1 * f[t];
        p = pn;
        j0 = k0; j1 = k1;
    }
#pragma unroll
    for (int t = 0; t < 8; t++) acc[t] += accB[t];

    // reduce across 16 edge slots (lane bits 2..5); q pieces stay separate
#pragma unroll
    for (int m = 4; m <= 32; m <<= 1) {
#pragma unroll
        for (int t = 0; t < 8; t++) acc[t] += __shfl_xor(acc[t], m);
    }

    // self term: + s[i]
    uint4 sv = *(const uint4*)(curt + (size_t)i * 16);
    float sf[8];
    bf8_unpack(sv, sf);
#pragma unroll
    for (int t = 0; t < 8; t++) acc[t] += sf[t];

    if (lane < 4) {   // slot==0; q == lane
        float d = dinv[i];
        float dd = d * d;
        uint4 pk;
        pk.x = (uint)f2bf(dd * acc[0]) | ((uint)f2bf(dd * acc[1]) << 16);
        pk.y = (uint)f2bf(dd * acc[2]) | ((uint)f2bf(dd * acc[3]) << 16);
        pk.z = (uint)f2bf(dd * acc[4]) | ((uint)f2bf(dd * acc[5]) << 16);
        pk.w = (uint)f2bf(dd * acc[6]) | ((uint)f2bf(dd * acc[7]) << 16);
        *(uint4*)((uint*)nxt + (size_t)tile * half_u + (size_t)i * 16 + lane * 4) = pk;
    }
}

// ------------- untiled hop (inline mode + final hop), tile-major state layout -------------
// one node per wave; lane = (g=edge slot 0..7, q=16B piece 0..7); q>>2 selects feature-tile.
// defer=0: out += temp[tidx]*dinv[i]*T_i every hop; writes s_next when tidx<Kf.
// tidx==Kf (final): combine deferred sum_{k} temp[k]/d*S_k, add temp[Kf]*d*T, log-softmax.
__global__ __launch_bounds__(256) void hopf_kernel(const int* __restrict__ ptr,
                                                   const int* __restrict__ csr_src,
                                                   const float* __restrict__ dinv,
                                                   const ushort* __restrict__ cur,
                                                   ushort* __restrict__ nxt,
                                                   float* __restrict__ out,
                                                   const float* __restrict__ temp,
                                                   const ushort* __restrict__ Sbase,
                                                   int tidx, int Kf, int defer, int n) {
    int i = (blockIdx.x * blockDim.x + threadIdx.x) >> 6;
    int lane = threadIdx.x & 63;
    if (i >= n) return;
    const int g = lane >> 3;
    const int q = lane & 7;
    const size_t nf = (size_t)n * HID;       // ushorts per state
    const size_t half_u = (size_t)n * 16;    // uints per feature-tile
    const size_t qoff = (size_t)(q >> 2) * half_u + (q & 3) * 4;
    const uint* curt = (const uint*)cur + qoff;

    int s = ptr[i];
    int e = ptr[i + 1];

    float acc[8] = {0.f, 0.f, 0.f, 0.f, 0.f, 0.f, 0.f, 0.f};
    float accB[8] = {0.f, 0.f, 0.f, 0.f, 0.f, 0.f, 0.f, 0.f};

    int rounds = (e - s + 31) >> 5;   // 32 edges per round (4 batches of 8)
    int p = s + g;
    int j0 = csr_src[(p      < e) ? p      : 0];
    int j1 = csr_src[(p + 8  < e) ? p + 8  : 0];
    int j2 = csr_src[(p + 16 < e) ? p + 16 : 0];
    int j3 = csr_src[(p + 24 < e) ? p + 24 : 0];

    for (int r = 0; r < rounds; r++) {
        int pn = p + 32;
        int k0 = csr_src[(pn      < e) ? pn      : 0];
        int k1 = csr_src[(pn + 8  < e) ? pn + 8  : 0];
        int k2 = csr_src[(pn + 16 < e) ? pn + 16 : 0];
        int k3 = csr_src[(pn + 24 < e) ? pn + 24 : 0];
        uint4 v0 = *(const uint4*)(curt + (size_t)j0 * 16);
        uint4 v1 = *(const uint4*)(curt + (size_t)j1 * 16);
        uint4 v2 = *(const uint4*)(curt + (size_t)j2 * 16);
        uint4 v3 = *(const uint4*)(curt + (size_t)j3 * 16);
        float w0 = (p      < e) ? 1.0f : 0.0f;
        float w1 = (p + 8  < e) ? 1.0f : 0.0f;
        float w2 = (p + 16 < e) ? 1.0f : 0.0f;
        float w3 = (p + 24 < e) ? 1.0f : 0.0f;
        float f[8];
        bf8_unpack(v0, f);
#pragma unroll
        for (int t = 0; t < 8; t++) acc[t] += w0 * f[t];
        bf8_unpack(v1, f);
#pragma unroll
        for (int t = 0; t < 8; t++) accB[t] += w1 * f[t];
        bf8_unpack(v2, f);
#pragma unroll
        for (int t = 0; t < 8; t++) acc[t] += w2 * f[t];
        bf8_unpack(v3, f);
#pragma unroll
        for (int t = 0; t < 8; t++) accB[t] += w3 * f[t];
        p = pn;
        j0 = k0; j1 = k1; j2 = k2; j3 = k3;
    }
#pragma unroll
    for (int t = 0; t < 8; t++) acc[t] += accB[t];

    // reduce across the 8 edge slots (lane bits 3..5); q pieces stay separate
#pragma unroll
    for (int m = 8; m <= 32; m <<= 1) {
#pragma unroll
        for (int t = 0; t < 8; t++) acc[t] += __shfl_xor(acc[t], m);
    }

    // self term: + s[i]
    uint4 sv = *(const uint4*)(curt + (size_t)i * 16);
    float sf[8];
    bf8_unpack(sv, sf);
#pragma unroll
    for (int t = 0; t < 8; t++) acc[t] += sf[t];

    if (lane < 8) {
        float d = dinv[i];
        float dd = d * d;
        float tk = temp[tidx] * d;
        if (tidx < Kf) {
            // write next state (tile-major)
            uint4 pk;
            pk.x = (uint)f2bf(dd * acc[0]) | ((uint)f2bf(dd * acc[1]) << 16);
            pk.y = (uint)f2bf(dd * acc[2]) | ((uint)f2bf(dd * acc[3]) << 16);
            pk.z = (uint)f2bf(dd * acc[4]) | ((uint)f2bf(dd * acc[5]) << 16);
            pk.w = (uint)f2bf(dd * acc[6]) | ((uint)f2bf(dd * acc[7]) << 16);
            *(uint4*)((uint*)nxt + qoff + (size_t)i * 16) = pk;

            if (!defer) {
                float* op = out + (size_t)i * HID + q * 8;
                float4 o0 = *(const float4*)(op);
                float4 o1 = *(const float4*)(op + 4);
                o0.x += tk * acc[0]; o0.y += tk * acc[1]; o0.z += tk * acc[2]; o0.w += tk * acc[3];
                o1.x += tk * acc[4]; o1.y += tk * acc[5]; o1.z += tk * acc[6]; o1.w += tk * acc[7];
                *(float4*)(op) = o0;
                *(float4*)(op + 4) = o1;
            }
        } else {
            // final hop: combine + fused log-softmax
            float* op = out + (size_t)i * HID + q * 8;
            float4 o0 = *(const float4*)(op);
            float4 o1 = *(const float4*)(op + 4);
            if (defer) {
                float rd = 1.0f / d;
                for (int k = 1; k < Kf; k++) {
                    const uint* sp = (const uint*)(Sbase + (size_t)k * nf) + qoff + (size_t)i * 16;
                    uint4 v = *(const uint4*)sp;
                    float f[8];
                    bf8_unpack(v, f);
                    float c = temp[k] * rd;
                    o0.x += c * f[0]; o0.y += c * f[1]; o0.z += c * f[2]; o0.w += c * f[3];
                    o1.x += c * f[4]; o1.y += c * f[5]; o1.z += c * f[6]; o1.w += c * f[7];
                }
            }
            o0.x += tk * acc[0]; o0.y += tk * acc[1]; o0.z += tk * acc[2]; o0.w += tk * acc[3];
            o1.x += tk * acc[4]; o1.y += tk * acc[5]; o1.z += tk * acc[6]; o1.w += tk * acc[7];

            // row log-softmax: lanes 0..7 hold the full 64-col row (8 vals each)
            float m = fmaxf(fmaxf(fmaxf(o0.x, o0.y), fmaxf(o0.z, o0.w)),
                            fmaxf(fmaxf(o1.x, o1.y), fmaxf(o1.z, o1.w)));
#pragma unroll
            for (int dm = 1; dm <= 4; dm <<= 1) m = fmaxf(m, __shfl_xor(m, dm));
            float ex = expf(o0.x - m) + expf(o0.y - m) + expf(o0.z - m) + expf(o0.w - m)
                     + expf(o1.x - m) + expf(o1.y - m) + expf(o1.z - m) + expf(o1.w - m);
#pragma unroll
            for (int dm = 1; dm <= 4; dm <<= 1) ex += __shfl_xor(ex, dm);
            float L = m + logf(ex);
            o0.x -= L; o0.y -= L; o0.z -= L; o0.w -= L;
            o1.x -= L; o1.y -= L; o1.z -= L; o1.w -= L;
            *(float4*)(op) = o0;
            *(float4*)(op + 4) = o1;
        }
    }
}

// ---------------- row log-softmax (only used if K==0) ----------------
__global__ __launch_bounds__(256) void lsm_kernel(float* __restrict__ out, int n) {
    int i = (blockIdx.x * blockDim.x + threadIdx.x) >> 6;
    int lane = threadIdx.x & 63;
    if (i >= n) return;
    size_t o = (size_t)i * HID + lane;
    float v = out[o];
    float m = v;
#pragma unroll
    for (int d = 32; d >= 1; d >>= 1) m = fmaxf(m, __shfl_xor(m, d));
    float ex = expf(v - m);
#pragma unroll
    for (int d = 32; d >= 1; d >>= 1) ex += __shfl_xor(ex, d);
    out[o] = v - m - logf(ex);
}

extern "C" void kernel_launch(void* const* d_in, const int* in_sizes, int n_in,
                              void* d_out, int out_size, void* d_ws, size_t ws_size,
                              hipStream_t stream) {
    const float* x    = (const float*)d_in[0];
    const int*   ei   = (const int*)d_in[1];
    const float* W1   = (const float*)d_in[2];
    const float* b1   = (const float*)d_in[3];
    const float* W2   = (const float*)d_in[4];
    const float* b2   = (const float*)d_in[5];
    const float* temp = (const float*)d_in[6];

    int n = in_sizes[0] / FEAT_IN;
    int E = in_sizes[1] / 2;
    int K = in_sizes[6] - 1;
    const int* row = ei;
    const int* col = ei + E;
    int nbkt = (n + NPB - 1) >> 7;

    char* ws = (char*)d_ws;
    size_t off = 0;
    auto alloc = [&](size_t bytes) -> void* {
        void* p = (void*)(ws + off);
        off += (bytes + 255) & ~(size_t)255;
        return p;
    };
    // common allocations
    float* dinv    = (float*)alloc((size_t)n * sizeof(float));
    int*   ptr     = (int*)alloc((size_t)(n + 1) * sizeof(int));
    int*   bcnt    = (int*)alloc((size_t)MAXB * sizeof(int));
    int*   boff    = (int*)alloc((size_t)(MAXB + 1) * sizeof(int));
    int*   bcur    = (int*)alloc((size_t)MAXB * sizeof(int));
    uint*  csr_tmp = (uint*)alloc((size_t)E * sizeof(uint));
    int*   csr_src = (int*)alloc((size_t)E * sizeof(int));
    ushort* w1s    = (ushort*)alloc(32768 * sizeof(ushort));
    ushort* w2s    = (ushort*)alloc(4096 * sizeof(ushort));

    size_t nf = (size_t)n * HID;
    size_t rem = (off <= ws_size) ? (ws_size - off) : 0;
    int defer = 0;
    ushort *A, *B, *S = nullptr;
    if (K > 1 && rem >= (size_t)K * nf * sizeof(ushort) + 1024) {
        defer = 1;
        S = (ushort*)alloc((size_t)K * nf * sizeof(ushort));  // S_0..S_{K-1}, stride nf
        A = S;
        B = S;  // unused in deferred mode
    } else {
        A = (ushort*)alloc(nf * sizeof(ushort));
        B = (ushort*)alloc(nf * sizeof(ushort));
        S = A;  // dummy (deferred loop never runs)
    }

    float* out = (float*)d_out;

    hipMemsetAsync(bcnt, 0, (size_t)nbkt * sizeof(int), stream);

    bcnt_kernel<<<256, 256, 0, stream>>>(col, bcnt, E, nbkt);
    bscan_kernel<<<1, 64, 0, stream>>>(bcnt, boff, bcur, ptr, nbkt, n, E);
    bscat_kernel<<<256, 1024, 0, stream>>>(row, col, bcur, csr_tmp, E, nbkt);
    bsort_kernel<<<nbkt, 256, 0, stream>>>(csr_tmp, boff, ptr, dinv, csr_src, n);
    swz_kernel<<<(32768 + 4096 + 255) / 256, 256, 0, stream>>>(W1, W2, w1s, w2s);

    int nmt = (n + 15) / 16;
    int mlp_blocks = (nmt + 1) / 2;  // 2 M-tiles per block, 2 waves per tile (K-split)
    mlp_kernel<<<mlp_blocks, 256, 0, stream>>>(x, w1s, b1, w2s, b2, temp, dinv, A, out, n);

    int ng = (n + 3) / 4;    // one node per wave, 4 waves per block
    if (defer) {
        // intermediate hops: tiled (no out access), 2 blocks (tiles) per node group
        for (int k = 0; k < K - 1; k++) {
            hopt2_kernel<<<2 * ng, 256, 0, stream>>>(ptr, csr_src, dinv,
                                                     S + (size_t)k * nf,
                                                     S + (size_t)(k + 1) * nf, n);
        }
        // final hop: untiled, combines deferred terms + fused log-softmax
        hopf_kernel<<<ng, 256, 0, stream>>>(ptr, csr_src, dinv, S + (size_t)(K - 1) * nf,
                                            S, out, temp, S, K, K, 1, n);
    } else {
        ushort* cur = A;
        ushort* nxt = B;
        for (int k = 0; k < K; k++) {
            hopf_kernel<<<ng, 256, 0, stream>>>(ptr, csr_src, dinv, cur, nxt, out,
                                                temp, S, k + 1, K, 0, n);
            ushort* t = cur; cur = nxt; nxt = t;
        }
    }
    if (K == 0) {
        lsm_kernel<<<ng, 256, 0, stream>>>(out, n);
    }
}

// Round 11
// 1025.170 us; speedup vs baseline: 1.2911x; 1.2911x over previous
//
#include <hip/hip_runtime.h>
#include <hip/hip_bf16.h>
#include <math.h>

#define FEAT_IN 500
#define HID 64
#define NPB 128        // nodes per bucket
#define MAXB 1024      // max buckets (supports n <= 131072)

typedef unsigned int uint;
typedef unsigned short ushort;
typedef __attribute__((ext_vector_type(8))) short bf16x8;
typedef __attribute__((ext_vector_type(4))) float f32x4;

__device__ inline ushort f2bf(float f) {
    uint u = __float_as_uint(f);
    uint r = (u + 0x7fff + ((u >> 16) & 1)) >> 16;
    return (ushort)r;
}

// pack two fp32 -> (bf16(a) | bf16(b)<<16), RNE
__device__ inline uint pk2(float a, float b) {
    uint ua = __float_as_uint(a), ub = __float_as_uint(b);
    ua = ua + 0x7fff + ((ua >> 16) & 1);
    ub = ub + 0x7fff + ((ub >> 16) & 1);
    return (ua >> 16) | (ub & 0xffff0000u);
}

__device__ inline void bf8_unpack(const uint4 v, float f[8]) {
    f[0] = __uint_as_float(v.x << 16);
    f[1] = __uint_as_float(v.x & 0xffff0000u);
    f[2] = __uint_as_float(v.y << 16);
    f[3] = __uint_as_float(v.y & 0xffff0000u);
    f[4] = __uint_as_float(v.z << 16);
    f[5] = __uint_as_float(v.z & 0xffff0000u);
    f[6] = __uint_as_float(v.w << 16);
    f[7] = __uint_as_float(v.w & 0xffff0000u);
}

// ---------------- phase A: per-bucket edge counts (LDS-aggregated) ----------------
__global__ __launch_bounds__(256) void bcnt_kernel(const int* __restrict__ col,
                                                   int* __restrict__ bcnt, int E, int nbkt) {
    __shared__ int cnt[MAXB];
    int tid = threadIdx.x;
    for (int j = tid; j < nbkt; j += 256) cnt[j] = 0;
    __syncthreads();
    int stride = gridDim.x * 256;
    for (int e = blockIdx.x * 256 + tid; e < E; e += stride) {
        atomicAdd(&cnt[col[e] >> 7], 1);
    }
    __syncthreads();
    for (int j = tid; j < nbkt; j += 256) {
        int v = cnt[j];
        if (v) atomicAdd(&bcnt[j], v);
    }
}

// ---------------- phase B: scan bucket counts -> boff, bcur; ptr[n]=E ----------------
__global__ void bscan_kernel(const int* __restrict__ bcnt, int* __restrict__ boff,
                             int* __restrict__ bcur, int* __restrict__ ptr,
                             int nbkt, int n, int E) {
    int lane = threadIdx.x;  // 64 threads
    int run = 0;
    for (int base = 0; base < nbkt; base += 64) {
        int i = base + lane;
        int v = (i < nbkt) ? bcnt[i] : 0;
        int sc = v;
#pragma unroll
        for (int d = 1; d < 64; d <<= 1) {
            int t = __shfl_up(sc, d);
            if (lane >= d) sc += t;
        }
        if (i < nbkt) {
            int ex = run + sc - v;
            boff[i] = ex;
            bcur[i] = ex;
        }
        run += __shfl(sc, 63);
    }
    if (lane == 0) {
        boff[nbkt] = E;
        ptr[n] = E;
    }
}

// ---------------- phase C: block-aggregated bucketed scatter ----------------
__global__ __launch_bounds__(1024) void bscat_kernel(const int* __restrict__ row,
                                                     const int* __restrict__ col,
                                                     int* __restrict__ bcur,
                                                     uint* __restrict__ csr_tmp,
                                                     int E, int nbkt) {
    __shared__ int cnt[MAXB];
    __shared__ int pos[MAXB];
    int tid = threadIdx.x;
    int chunk = (E + gridDim.x - 1) / gridDim.x;
    int c0 = blockIdx.x * chunk;
    int c1 = min(E, c0 + chunk);
    for (int j = tid; j < nbkt; j += 1024) cnt[j] = 0;
    __syncthreads();
    for (int e = c0 + tid; e < c1; e += 1024) atomicAdd(&cnt[col[e] >> 7], 1);
    __syncthreads();
    for (int j = tid; j < nbkt; j += 1024) {
        int v = cnt[j];
        pos[j] = v ? atomicAdd(&bcur[j], v) : 0;
    }
    __syncthreads();
    for (int e = c0 + tid; e < c1; e += 1024) {
        int c = col[e];
        int j = c >> 7;
        int r = atomicAdd(&pos[j], 1);
        csr_tmp[r] = ((uint)row[e] << 7) | (uint)(c & (NPB - 1));
    }
}

// ---------------- phase D: per-bucket node sort -> csr_src, ptr, dinv ----------------
__global__ __launch_bounds__(256) void bsort_kernel(const uint* __restrict__ csr_tmp,
                                                    const int* __restrict__ boff,
                                                    int* __restrict__ ptr,
                                                    float* __restrict__ dinv,
                                                    int* __restrict__ csr_src,
                                                    int n) {
    __shared__ int degl[NPB];
    __shared__ int offl[NPB];
    int b = blockIdx.x;
    int tid = threadIdx.x;
    int t0 = boff[b], t1 = boff[b + 1];
    if (tid < NPB) degl[tid] = 0;
    __syncthreads();
    for (int p = t0 + tid; p < t1; p += 256) {
        uint pk = csr_tmp[p];
        atomicAdd(&degl[pk & (NPB - 1)], 1);
    }
    __syncthreads();
    if (tid < 64) {
        int v0 = degl[tid];
        int s0 = v0;
#pragma unroll
        for (int d = 1; d < 64; d <<= 1) {
            int t = __shfl_up(s0, d);
            if (tid >= d) s0 += t;
        }
        int tot0 = __shfl(s0, 63);
        int v1 = degl[64 + tid];
        int s1 = v1;
#pragma unroll
        for (int d = 1; d < 64; d <<= 1) {
            int t = __shfl_up(s1, d);
            if (tid >= d) s1 += t;
        }
        offl[tid] = s0 - v0;
        offl[64 + tid] = tot0 + s1 - v1;
    }
    __syncthreads();
    if (tid < NPB) {
        int node = b * NPB + tid;
        if (node < n) {
            ptr[node] = t0 + offl[tid];
            dinv[node] = rsqrtf((float)(degl[tid] + 1));  // +1 self loop
        }
    }
    __syncthreads();
    for (int p = t0 + tid; p < t1; p += 256) {
        uint pk = csr_tmp[p];
        int l = pk & (NPB - 1);
        int r = t0 + atomicAdd(&offl[l], 1);
        csr_src[r] = (int)(pk >> 7);
    }
}

// -------- swizzle W1 (500x64, pad K->512) and W2 (64x64) into MFMA B-frag order --------
__global__ void swz_kernel(const float* __restrict__ W1, const float* __restrict__ W2,
                           ushort* __restrict__ w1s, ushort* __restrict__ w2s) {
    int idx = blockIdx.x * blockDim.x + threadIdx.x;  // [0, 36864)
    if (idx < 32768) {
        int j = idx & 7;
        int l = (idx >> 3) & 63;
        int t = (idx >> 9) & 3;
        int c = idx >> 11;
        int k = c * 32 + (l >> 4) * 8 + j;
        int nn = t * 16 + (l & 15);
        float v = (k < FEAT_IN) ? W1[(size_t)k * HID + nn] : 0.0f;
        w1s[idx] = f2bf(v);
    } else if (idx < 32768 + 4096) {
        int r = idx - 32768;
        int j = r & 7;
        int l = (r >> 3) & 63;
        int t = (r >> 9) & 3;
        int c = r >> 11;
        int k = c * 32 + (l >> 4) * 8 + j;
        int nn = t * 16 + (l & 15);
        w2s[r] = f2bf(W2[(size_t)k * HID + nn]);
    }
}

// ------------- MFMA MLP, K-split: 2 waves per M-tile (each 8 K-chunks), partials in LDS.
// h=relu(xW1+b1); h2=hW2+b2; A=bf16(dinv*h2) flat; out=temp[0]*h2
__global__ __launch_bounds__(256) void mlp_kernel(const float* __restrict__ x,
                                                  const ushort* __restrict__ w1s,
                                                  const float* __restrict__ b1,
                                                  const ushort* __restrict__ w2s,
                                                  const float* __restrict__ b2,
                                                  const float* __restrict__ temp,
                                                  const float* __restrict__ dinv,
                                                  ushort* __restrict__ A,
                                                  float* __restrict__ out, int n) {
    __shared__ float pacc[2][2][16][65];   // [tile][khalf][row][col(+pad)]
    __shared__ ushort hls[2][16 * 72];     // bf16 h1 per tile, row stride 72
    const int tid = threadIdx.x;
    const int lane = tid & 63;
    const int wv = tid >> 6;   // 0..3
    const int tl = wv >> 1;    // tile within block
    const int kh = wv & 1;     // K half
    const int g = lane >> 4;
    const int c15 = lane & 15;
    const int nmt = (n + 15) / 16;
    int mt = blockIdx.x * 2 + tl;
    bool mtok = (mt < nmt);
    float t0 = temp[0];

    f32x4 acc[4] = {{0.f, 0.f, 0.f, 0.f}, {0.f, 0.f, 0.f, 0.f},
                    {0.f, 0.f, 0.f, 0.f}, {0.f, 0.f, 0.f, 0.f}};
    int row = mt * 16 + c15;
    bool rok = mtok && (row < n);
    const float* xr = x + (size_t)row * FEAT_IN;

    if (mtok) {
        const int cbeg = kh * 8;
        const int cend = kh ? 15 : 8;  // full chunks; kh=1 tail (c=15) separate
        // pipelined, prefetch distance 2
        float4 L0 = {0.f, 0.f, 0.f, 0.f}, H0 = L0, L1 = L0, H1 = L0;
        if (rok) {
            L0 = *(const float4*)(xr + cbeg * 32 + g * 8);
            H0 = *(const float4*)(xr + cbeg * 32 + g * 8 + 4);
            L1 = *(const float4*)(xr + (cbeg + 1) * 32 + g * 8);
            H1 = *(const float4*)(xr + (cbeg + 1) * 32 + g * 8 + 4);
        }
        for (int c = cbeg; c < cend; c++) {
            float4 Ln = {0.f, 0.f, 0.f, 0.f}, Hn = Ln;
            int cn = c + 2;
            if (rok && cn < cend) {
                Ln = *(const float4*)(xr + cn * 32 + g * 8);
                Hn = *(const float4*)(xr + cn * 32 + g * 8 + 4);
            }
            uint4 au;
            au.x = pk2(L0.x, L0.y);
            au.y = pk2(L0.z, L0.w);
            au.z = pk2(H0.x, H0.y);
            au.w = pk2(H0.z, H0.w);
            bf16x8 a = *(bf16x8*)&au;
            const ushort* wp = w1s + ((size_t)c * 4) * 512 + lane * 8;
#pragma unroll
            for (int t = 0; t < 4; t++) {
                bf16x8 b = *(const bf16x8*)(wp + t * 512);
                acc[t] = __builtin_amdgcn_mfma_f32_16x16x32_bf16(a, b, acc[t], 0, 0, 0);
            }
            L0 = L1; H0 = H1; L1 = Ln; H1 = Hn;
        }
        if (kh) {  // tail chunk c=15 (k = 480..511, valid < 500)
            float v[8];
#pragma unroll
            for (int j = 0; j < 8; j++) {
                int k = 480 + g * 8 + j;
                v[j] = (rok && k < FEAT_IN) ? xr[k] : 0.0f;
            }
            uint4 au;
            au.x = pk2(v[0], v[1]);
            au.y = pk2(v[2], v[3]);
            au.z = pk2(v[4], v[5]);
            au.w = pk2(v[6], v[7]);
            bf16x8 a = *(bf16x8*)&au;
            const ushort* wp = w1s + (size_t)15 * 4 * 512 + lane * 8;
#pragma unroll
            for (int t = 0; t < 4; t++) {
                bf16x8 b = *(const bf16x8*)(wp + t * 512);
                acc[t] = __builtin_amdgcn_mfma_f32_16x16x32_bf16(a, b, acc[t], 0, 0, 0);
            }
        }
        // write partial sums
#pragma unroll
        for (int t = 0; t < 4; t++) {
#pragma unroll
            for (int r = 0; r < 4; r++) {
                pacc[tl][kh][g * 4 + r][t * 16 + c15] = acc[t][r];
            }
        }
    }
    __syncthreads();

    // combine partials -> h1 bf16 (wave (tl,kh) does its tile's col-half)
    if (mtok) {
        int rrow = lane & 15;
        int cg = lane >> 4;
        int colbase = kh * 32 + cg * 8;
#pragma unroll
        for (int cc = 0; cc < 8; cc++) {
            int colc = colbase + cc;
            float h = pacc[tl][0][rrow][colc] + pacc[tl][1][rrow][colc] + b1[colc];
            hls[tl][rrow * 72 + colc] = f2bf(fmaxf(h, 0.0f));
        }
    }
    __syncthreads();
    if (!mtok) return;

    // GEMM2: h1(16x64) @ W2(64x64); wave (tl,kh) computes output cols [kh*32, kh*32+32)
    f32x4 acc2[2] = {{0.f, 0.f, 0.f, 0.f}, {0.f, 0.f, 0.f, 0.f}};
#pragma unroll
    for (int c2 = 0; c2 < 2; c2++) {
        bf16x8 a2 = *(const bf16x8*)(hls[tl] + c15 * 72 + c2 * 32 + g * 8);
#pragma unroll
        for (int tt = 0; tt < 2; tt++) {
            int t = kh * 2 + tt;
            bf16x8 b = *(const bf16x8*)(w2s + ((size_t)(c2 * 4 + t)) * 512 + lane * 8);
            acc2[tt] = __builtin_amdgcn_mfma_f32_16x16x32_bf16(a2, b, acc2[tt], 0, 0, 0);
        }
    }

    // epilogue: A = bf16(dinv*h2) flat; out = temp[0]*h2
#pragma unroll
    for (int tt = 0; tt < 2; tt++) {
        int t = kh * 2 + tt;
        float b2v = b2[t * 16 + c15];
#pragma unroll
        for (int r = 0; r < 4; r++) {
            int orow = mt * 16 + g * 4 + r;
            if (orow < n) {
                float dres = acc2[tt][r] + b2v;
                size_t o = (size_t)orow * HID + t * 16 + c15;
                A[o] = f2bf(dinv[orow] * dres);
                out[o] = t0 * dres;
            }
        }
    }
}

// ------------- one propagation hop on scaled state s = dinv*u, full 128B rows -------------
// one node per wave; lane = (g=edge slot 0..7, q=16B piece 0..7).
// T_i = sum_{j in N(i)} s[j] + s[i];  s_next[i] = dinv[i]^2*T_i
// defer=0: out += temp[tidx]*dinv[i]*T_i every hop (inline mode).
// defer=1: intermediate hops don't touch out; final hop (tidx==Kf) combines
//          out = t0*h2 + sum_{k=1..Kf-1} temp[k]/d * S_k[i] + temp[Kf]*d*T, then log-softmax.
__global__ __launch_bounds__(256) void hopf_kernel(const int* __restrict__ ptr,
                                                   const int* __restrict__ csr_src,
                                                   const float* __restrict__ dinv,
                                                   const ushort* __restrict__ cur,
                                                   ushort* __restrict__ nxt,
                                                   float* __restrict__ out,
                                                   const float* __restrict__ temp,
                                                   const ushort* __restrict__ Sbase,
                                                   int tidx, int Kf, int defer, int n) {
    int i = (blockIdx.x * blockDim.x + threadIdx.x) >> 6;
    int lane = threadIdx.x & 63;
    if (i >= n) return;
    const int g = lane >> 3;
    const int q = lane & 7;
    const size_t nf = (size_t)n * HID;

    int s = ptr[i];
    int e = ptr[i + 1];
    const uint* curu = (const uint*)cur;

    float acc[8] = {0.f, 0.f, 0.f, 0.f, 0.f, 0.f, 0.f, 0.f};
    float accB[8] = {0.f, 0.f, 0.f, 0.f, 0.f, 0.f, 0.f, 0.f};

    int rounds = (e - s + 31) >> 5;   // 32 edges per round (4 batches of 8)
    int p = s + g;
    // preload batch indices (masked lanes clamp to csr_src[0]: one hot line, weight 0)
    int j0 = csr_src[(p      < e) ? p      : 0];
    int j1 = csr_src[(p + 8  < e) ? p + 8  : 0];
    int j2 = csr_src[(p + 16 < e) ? p + 16 : 0];
    int j3 = csr_src[(p + 24 < e) ? p + 24 : 0];

    for (int r = 0; r < rounds; r++) {
        int pn = p + 32;
        // prefetch next round's indices (independent of this round's gathers)
        int k0 = csr_src[(pn      < e) ? pn      : 0];
        int k1 = csr_src[(pn + 8  < e) ? pn + 8  : 0];
        int k2 = csr_src[(pn + 16 < e) ? pn + 16 : 0];
        int k3 = csr_src[(pn + 24 < e) ? pn + 24 : 0];
        // 4 independent 16B gathers in flight (full 128B rows across 8 q-lanes)
        uint4 v0 = *(const uint4*)(curu + (size_t)j0 * 32 + q * 4);
        uint4 v1 = *(const uint4*)(curu + (size_t)j1 * 32 + q * 4);
        uint4 v2 = *(const uint4*)(curu + (size_t)j2 * 32 + q * 4);
        uint4 v3 = *(const uint4*)(curu + (size_t)j3 * 32 + q * 4);
        float w0 = (p      < e) ? 1.0f : 0.0f;
        float w1 = (p + 8  < e) ? 1.0f : 0.0f;
        float w2 = (p + 16 < e) ? 1.0f : 0.0f;
        float w3 = (p + 24 < e) ? 1.0f : 0.0f;
        float f[8];
        bf8_unpack(v0, f);
#pragma unroll
        for (int t = 0; t < 8; t++) acc[t] += w0 * f[t];
        bf8_unpack(v1, f);
#pragma unroll
        for (int t = 0; t < 8; t++) accB[t] += w1 * f[t];
        bf8_unpack(v2, f);
#pragma unroll
        for (int t = 0; t < 8; t++) acc[t] += w2 * f[t];
        bf8_unpack(v3, f);
#pragma unroll
        for (int t = 0; t < 8; t++) accB[t] += w3 * f[t];
        p = pn;
        j0 = k0; j1 = k1; j2 = k2; j3 = k3;
    }
#pragma unroll
    for (int t = 0; t < 8; t++) acc[t] += accB[t];

    // reduce across the 8 edge slots (lane bits 3..5); q pieces stay separate
#pragma unroll
    for (int m = 8; m <= 32; m <<= 1) {
#pragma unroll
        for (int t = 0; t < 8; t++) acc[t] += __shfl_xor(acc[t], m);
    }

    // self term: + s[i]
    uint4 sv = *(const uint4*)(curu + (size_t)i * 32 + q * 4);
    float sf[8];
    bf8_unpack(sv, sf);
#pragma unroll
    for (int t = 0; t < 8; t++) acc[t] += sf[t];

    if (lane < 8) {
        float d = dinv[i];
        float dd = d * d;
        float tk = temp[tidx] * d;
        if (tidx < Kf) {
            // write next state
            uint4 pk;
            pk.x = (uint)f2bf(dd * acc[0]) | ((uint)f2bf(dd * acc[1]) << 16);
            pk.y = (uint)f2bf(dd * acc[2]) | ((uint)f2bf(dd * acc[3]) << 16);
            pk.z = (uint)f2bf(dd * acc[4]) | ((uint)f2bf(dd * acc[5]) << 16);
            pk.w = (uint)f2bf(dd * acc[6]) | ((uint)f2bf(dd * acc[7]) << 16);
            *(uint4*)((uint*)nxt + (size_t)i * 32 + q * 4) = pk;

            if (!defer) {
                float* op = out + (size_t)i * HID + q * 8;
                float4 o0 = *(const float4*)(op);
                float4 o1 = *(const float4*)(op + 4);
                o0.x += tk * acc[0]; o0.y += tk * acc[1]; o0.z += tk * acc[2]; o0.w += tk * acc[3];
                o1.x += tk * acc[4]; o1.y += tk * acc[5]; o1.z += tk * acc[6]; o1.w += tk * acc[7];
                *(float4*)(op) = o0;
                *(float4*)(op + 4) = o1;
            }
        } else {
            // final hop: combine + fused log-softmax
            float* op = out + (size_t)i * HID + q * 8;
            float4 o0 = *(const float4*)(op);
            float4 o1 = *(const float4*)(op + 4);
            if (defer) {
                float rd = 1.0f / d;
                for (int k = 1; k < Kf; k++) {
                    const uint* sp = (const uint*)(Sbase + (size_t)k * nf) + (size_t)i * 32 + q * 4;
                    uint4 v = *(const uint4*)sp;
                    float f[8];
                    bf8_unpack(v, f);
                    float c = temp[k] * rd;
                    o0.x += c * f[0]; o0.y += c * f[1]; o0.z += c * f[2]; o0.w += c * f[3];
                    o1.x += c * f[4]; o1.y += c * f[5]; o1.z += c * f[6]; o1.w += c * f[7];
                }
            }
            o0.x += tk * acc[0]; o0.y += tk * acc[1]; o0.z += tk * acc[2]; o0.w += tk * acc[3];
            o1.x += tk * acc[4]; o1.y += tk * acc[5]; o1.z += tk * acc[6]; o1.w += tk * acc[7];

            // row log-softmax: lanes 0..7 hold the full 64-col row (8 vals each)
            float m = fmaxf(fmaxf(fmaxf(o0.x, o0.y), fmaxf(o0.z, o0.w)),
                            fmaxf(fmaxf(o1.x, o1.y), fmaxf(o1.z, o1.w)));
#pragma unroll
            for (int dm = 1; dm <= 4; dm <<= 1) m = fmaxf(m, __shfl_xor(m, dm));
            float ex = expf(o0.x - m) + expf(o0.y - m) + expf(o0.z - m) + expf(o0.w - m)
                     + expf(o1.x - m) + expf(o1.y - m) + expf(o1.z - m) + expf(o1.w - m);
#pragma unroll
            for (int dm = 1; dm <= 4; dm <<= 1) ex += __shfl_xor(ex, dm);
            float L = m + logf(ex);
            o0.x -= L; o0.y -= L; o0.z -= L; o0.w -= L;
            o1.x -= L; o1.y -= L; o1.z -= L; o1.w -= L;
            *(float4*)(op) = o0;
            *(float4*)(op + 4) = o1;
        }
    }
}

// ---------------- row log-softmax (only used if K==0) ----------------
__global__ __launch_bounds__(256) void lsm_kernel(float* __restrict__ out, int n) {
    int i = (blockIdx.x * blockDim.x + threadIdx.x) >> 6;
    int lane = threadIdx.x & 63;
    if (i >= n) return;
    size_t o = (size_t)i * HID + lane;
    float v = out[o];
    float m = v;
#pragma unroll
    for (int d = 32; d >= 1; d >>= 1) m = fmaxf(m, __shfl_xor(m, d));
    float ex = expf(v - m);
#pragma unroll
    for (int d = 32; d >= 1; d >>= 1) ex += __shfl_xor(ex, d);
    out[o] = v - m - logf(ex);
}

extern "C" void kernel_launch(void* const* d_in, const int* in_sizes, int n_in,
                              void* d_out, int out_size, void* d_ws, size_t ws_size,
                              hipStream_t stream) {
    const float* x    = (const float*)d_in[0];
    const int*   ei   = (const int*)d_in[1];
    const float* W1   = (const float*)d_in[2];
    const float* b1   = (const float*)d_in[3];
    const float* W2   = (const float*)d_in[4];
    const float* b2   = (const float*)d_in[5];
    const float* temp = (const float*)d_in[6];

    int n = in_sizes[0] / FEAT_IN;
    int E = in_sizes[1] / 2;
    int K = in_sizes[6] - 1;
    const int* row = ei;
    const int* col = ei + E;
    int nbkt = (n + NPB - 1) >> 7;

    char* ws = (char*)d_ws;
    size_t off = 0;
    auto alloc = [&](size_t bytes) -> void* {
        void* p = (void*)(ws + off);
        off += (bytes + 255) & ~(size_t)255;
        return p;
    };
    // common allocations
    float* dinv    = (float*)alloc((size_t)n * sizeof(float));
    int*   ptr     = (int*)alloc((size_t)(n + 1) * sizeof(int));
    int*   bcnt    = (int*)alloc((size_t)MAXB * sizeof(int));
    int*   boff    = (int*)alloc((size_t)(MAXB + 1) * sizeof(int));
    int*   bcur    = (int*)alloc((size_t)MAXB * sizeof(int));
    uint*  csr_tmp = (uint*)alloc((size_t)E * sizeof(uint));
    int*   csr_src = (int*)alloc((size_t)E * sizeof(int));
    ushort* w1s    = (ushort*)alloc(32768 * sizeof(ushort));
    ushort* w2s    = (ushort*)alloc(4096 * sizeof(ushort));

    size_t nf = (size_t)n * HID;
    size_t rem = (off <= ws_size) ? (ws_size - off) : 0;
    int defer = 0;
    ushort *A, *B, *S = nullptr;
    if (K > 1 && rem >= (size_t)K * nf * sizeof(ushort) + 1024) {
        defer = 1;
        S = (ushort*)alloc((size_t)K * nf * sizeof(ushort));  // S_0..S_{K-1}, stride nf
        A = S;
        B = S;  // unused in deferred mode
    } else {
        A = (ushort*)alloc(nf * sizeof(ushort));
        B = (ushort*)alloc(nf * sizeof(ushort));
        S = A;  // dummy (deferred loop never runs)
    }

    float* out = (float*)d_out;

    hipMemsetAsync(bcnt, 0, (size_t)nbkt * sizeof(int), stream);

    bcnt_kernel<<<256, 256, 0, stream>>>(col, bcnt, E, nbkt);
    bscan_kernel<<<1, 64, 0, stream>>>(bcnt, boff, bcur, ptr, nbkt, n, E);
    bscat_kernel<<<256, 1024, 0, stream>>>(row, col, bcur, csr_tmp, E, nbkt);
    bsort_kernel<<<nbkt, 256, 0, stream>>>(csr_tmp, boff, ptr, dinv, csr_src, n);
    swz_kernel<<<(32768 + 4096 + 255) / 256, 256, 0, stream>>>(W1, W2, w1s, w2s);

    int nmt = (n + 15) / 16;
    int mlp_blocks = (nmt + 1) / 2;  // 2 M-tiles per block, 2 waves per tile (K-split)
    mlp_kernel<<<mlp_blocks, 256, 0, stream>>>(x, w1s, b1, w2s, b2, temp, dinv, A, out, n);

    int hop_blocks = (n + 3) / 4;    // one node per wave
    if (defer) {
        for (int k = 0; k < K; k++) {
            const ushort* cur = S + (size_t)k * nf;
            ushort* nxt = (k + 1 < K) ? (S + (size_t)(k + 1) * nf) : S;  // final hop never writes
            hopf_kernel<<<hop_blocks, 256, 0, stream>>>(ptr, csr_src, dinv, cur, nxt, out,
                                                        temp, S, k + 1, K, 1, n);
        }
    } else {
        ushort* cur = A;
        ushort* nxt = B;
        for (int k = 0; k < K; k++) {
            hopf_kernel<<<hop_blocks, 256, 0, stream>>>(ptr, csr_src, dinv, cur, nxt, out,
                                                        temp, S, k + 1, K, 0, n);
            ushort* t = cur; cur = nxt; nxt = t;
        }
    }
    if (K == 0) {
        lsm_kernel<<<hop_blocks, 256, 0, stream>>>(out, n);
    }
}